// Round 14
// baseline (452.772 us; speedup 1.0000x reference)
//
#include <hip/hip_runtime.h>
#include <math.h>

typedef _Float16 f16;
typedef f16 f16x8 __attribute__((ext_vector_type(8)));
typedef float f32x4 __attribute__((ext_vector_type(4)));

#define MFMA16(a,b,c) __builtin_amdgcn_mfma_f32_16x16x32_f16(a,b,c,0,0,0)

static __device__ __forceinline__ f16x8 ld8(const f16* p) { return *(const f16x8*)p; }

static __device__ __forceinline__ float exp2a(float x) {
    float r; asm("v_exp_f32 %0, %1" : "=v"(r) : "v"(x)); return r;
}

// bijective XCD-chunking remap (m204)
static __device__ __forceinline__ int xcd_remap(int flat, int nwg) {
    int q = nwg >> 3, r = nwg & 7;
    int xcd = flat & 7, pos = flat >> 3;
    return (xcd < r ? xcd * (q + 1) : r * (q + 1) + (xcd - r) * q) + pos;
}

#if __has_builtin(__builtin_amdgcn_global_load_lds)
#define GLL16(g, lptr) __builtin_amdgcn_global_load_lds((const __attribute__((address_space(1))) void*)(g), (__attribute__((address_space(3))) void*)(lptr), 16, 0, 0)
#else
#define GLL16(g, lptr) do { *(int4*)(lptr) = *(const int4*)(g); } while (0)
#endif

// ---------------- merged: gating MLP stage 1 (blocks 0..511, K-split=8) + weight transposes ----------------
__global__ __launch_bounds__(256) void k_mlp1t(const float* __restrict__ h, const float* __restrict__ w1,
                                               const float* __restrict__ wq, const float* __restrict__ wk,
                                               const float* __restrict__ wv, const float* __restrict__ wo,
                                               double* __restrict__ part, f16* __restrict__ h16,
                                               f16* __restrict__ wqkvt, f16* __restrict__ wot) {
    int blk = blockIdx.x;
    int tid = threadIdx.x;
    if (blk < 512) {
        __shared__ float hs[64 * 68];
        __shared__ float ws[64 * 64];
        int rb = blk & 63, ks = blk >> 6;
        int jq = tid & 15, rt = tid >> 4;
        double acc[4][4];
        #pragma unroll
        for (int r = 0; r < 4; ++r)
            #pragma unroll
            for (int q = 0; q < 4; ++q) acc[r][q] = 0.0;

        float4 hreg[4], wreg[4];
        int hrow[4], hcq[4], wc[4], wq4[4];
        #pragma unroll
        for (int i = 0; i < 4; ++i) {
            int fl = i * 256 + tid;
            hrow[i] = fl >> 4; hcq[i] = fl & 15;
            wc[i] = fl >> 4;   wq4[i] = fl & 15;
        }
        #define LOADCH(c8) do {                                                                  \
            _Pragma("unroll")                                                                     \
            for (int i = 0; i < 4; ++i) {                                                         \
                hreg[i] = *(const float4*)&h[(size_t)(rb*64 + hrow[i])*2048 + ks*256 + (c8)*64 + hcq[i]*4]; \
                wreg[i] = *(const float4*)&w1[(size_t)(ks*256 + (c8)*64 + wc[i])*64 + wq4[i]*4];  \
            }                                                                                     \
        } while (0)

        LOADCH(0);
        for (int c8 = 0; c8 < 4; ++c8) {
            __syncthreads();
            #pragma unroll
            for (int i = 0; i < 4; ++i) {
                *(float4*)&hs[hrow[i]*68 + hcq[i]*4] = hreg[i];
                *(float4*)&ws[wc[i]*64 + wq4[i]*4] = wreg[i];
                const float* hp = (const float*)&hreg[i];
                f16 h4[4];
                #pragma unroll
                for (int z = 0; z < 4; ++z) h4[z] = (f16)hp[z];
                *(float*)&h16[(size_t)(rb*64 + hrow[i])*2048 + ks*256 + c8*64 + hcq[i]*4] = *(float*)h4;
                *(float*)(&h16[(size_t)(rb*64 + hrow[i])*2048 + ks*256 + c8*64 + hcq[i]*4 + 2]) = *(((float*)h4)+1);
            }
            __syncthreads();
            if (c8 < 3) LOADCH(c8 + 1);
            #pragma unroll 4
            for (int cg = 0; cg < 64; cg += 4) {
                float4 ha[4], wa[4];
                #pragma unroll
                for (int r = 0; r < 4; ++r) ha[r] = *(const float4*)&hs[(rt + 16*r)*68 + cg];
                #pragma unroll
                for (int cc = 0; cc < 4; ++cc) wa[cc] = *(const float4*)&ws[(cg + cc)*64 + jq*4];
                #pragma unroll
                for (int cc = 0; cc < 4; ++cc) {
                    const float* wap = (const float*)&wa[cc];
                    double wd0 = (double)wap[0], wd1 = (double)wap[1], wd2 = (double)wap[2], wd3 = (double)wap[3];
                    #pragma unroll
                    for (int r = 0; r < 4; ++r) {
                        double hv = (double)((const float*)&ha[r])[cc];
                        acc[r][0] = fma(hv, wd0, acc[r][0]);
                        acc[r][1] = fma(hv, wd1, acc[r][1]);
                        acc[r][2] = fma(hv, wd2, acc[r][2]);
                        acc[r][3] = fma(hv, wd3, acc[r][3]);
                    }
                }
            }
        }
        #pragma unroll
        for (int r = 0; r < 4; ++r)
            #pragma unroll
            for (int q = 0; q < 4; ++q)
                part[((size_t)ks*4096 + rb*64 + rt + 16*r)*64 + jq*4 + q] = acc[r][q];
        #undef LOADCH
    } else {
        __shared__ float tile[32][33];
        int tb = blk - 512;
        int bx = tb % 160;
        int y0 = (tb / 160) * 32;
        int tx = tid & 31, ty = tid >> 5;
        const float* in; int inCols, colBase, rowOff; f16* out;
        if (bx < 64)      { in = wq; inCols = 2048; colBase = bx * 32;        rowOff = colBase;        out = wqkvt; }
        else if (bx < 80) { in = wk; inCols = 512;  colBase = (bx - 64) * 32; rowOff = 2048 + colBase; out = wqkvt; }
        else if (bx < 96) { in = wv; inCols = 512;  colBase = (bx - 80) * 32; rowOff = 2560 + colBase; out = wqkvt; }
        else              { in = wo; inCols = 2048; colBase = (bx - 96) * 32; rowOff = colBase;        out = wot; }
        int x = colBase + tx;
        #pragma unroll
        for (int i = 0; i < 4; ++i)
            tile[ty + i*8][tx] = in[(size_t)(y0 + ty + i*8) * inCols + x];
        __syncthreads();
        #pragma unroll
        for (int i = 0; i < 4; ++i)
            out[(size_t)(rowOff + ty + i*8) * 2048 + y0 + tx] = (f16)tile[tx][ty + i*8];
    }
}

// ---------------- gating MLP stage 2 (8-way K-split reduce) ----------------
__global__ __launch_bounds__(256) void k_mlp2(const double* __restrict__ part, const float* __restrict__ b1,
                                              const float* __restrict__ w2, const float* __restrict__ b2,
                                              double* __restrict__ logitsD, float* __restrict__ iw) {
    int tid = threadIdx.x;
    int j = tid & 63, rq = tid >> 6;
    int row = blockIdx.x * 4 + rq;
    double s = 0.0;
    #pragma unroll
    for (int ks = 0; ks < 8; ++ks) s += part[((size_t)ks*4096 + row)*64 + j];
    double t = tanh(s + (double)b1[j]);
    double v = t * (double)w2[j];
    #pragma unroll
    for (int o = 32; o > 0; o >>= 1) v += __shfl_down(v, o);
    if (j == 0) {
        double lg = v + (double)b2[0] - 1.8562979903656263; // log(4096/640)
        logitsD[row] = lg;
        iw[row] = (float)(1.0 / (1.0 + exp(-lg)));
    }
}

// ---------------- top-2048 of 4096 via MSB radix select (order-free set) ----------------
__global__ __launch_bounds__(1024) void k_topk(const double* __restrict__ logitsD, int* __restrict__ sel) {
    __shared__ unsigned long long keys[4096];
    __shared__ unsigned int hist[2048];
    __shared__ unsigned int bcast[2];
    __shared__ unsigned int cA, cB;
    int tid = threadIdx.x;
    for (int i = tid; i < 4096; i += 1024) {
        unsigned long long u = (unsigned long long)__double_as_longlong(logitsD[i]);
        keys[i] = (u >> 63) ? ~u : (u | 0x8000000000000000ull);
    }
    if (tid == 0) { cA = 0; cB = 0; }
    unsigned long long Tpart = 0;
    unsigned int need = 2048;
    #pragma unroll 1
    for (int lvl = 0; lvl < 6; ++lvl) {
        int shift = (lvl < 5) ? (53 - 11*lvl) : 0;
        int width = (lvl < 5) ? 11 : 9;
        unsigned int nb = 1u << width;
        int hiShift = shift + width;
        for (int i = tid; i < (int)nb; i += 1024) hist[i] = 0;
        __syncthreads();
        for (int i = tid; i < 4096; i += 1024) {
            unsigned long long k = keys[i];
            bool cand = (lvl == 0) || ((k >> hiShift) == (Tpart >> hiShift));
            if (cand) atomicAdd(&hist[(unsigned int)(k >> shift) & (nb - 1u)], 1u);
        }
        __syncthreads();
        if (tid < 64) {
            int chunk = (int)nb >> 6;
            int base = (int)nb - (tid + 1) * chunk;
            unsigned int sum = 0;
            for (int jj = 0; jj < chunk; ++jj) sum += hist[base + jj];
            unsigned int pre = sum;
            #pragma unroll
            for (int o = 1; o < 64; o <<= 1) {
                unsigned int t = __shfl_up(pre, o);
                if (tid >= o) pre += t;
            }
            unsigned int preEx = pre - sum;
            if (preEx < need && need <= pre) {
                unsigned int cum = preEx;
                for (int jj = chunk - 1; jj >= 0; --jj) {
                    unsigned int c = hist[base + jj];
                    if (cum + c >= need) { bcast[0] = (unsigned int)(base + jj); bcast[1] = need - cum; break; }
                    cum += c;
                }
            }
        }
        __syncthreads();
        Tpart |= ((unsigned long long)bcast[0]) << shift;
        need = bcast[1];
        __syncthreads();
    }
    unsigned int G = 2048 - need;
    for (int i = tid; i < 4096; i += 1024) {
        unsigned long long k = keys[i];
        if (k > Tpart) { unsigned int p = atomicAdd(&cA, 1u); sel[p] = i; }
        else if (k == Tpart) { unsigned int q = atomicAdd(&cB, 1u); if (q < need) sel[G + q] = i; }
    }
}

// ---------------- gemm1 with fused RMSnorm(+RoPE) epilogue: A[4096][2048] x wqkvt^T -> qr / kn / qkvraw(V) ----
// Each 128-col block spans exactly one head. Q (col0<2048): norm+RoPE -> qr f16.
// K (2048<=col0<2560): norm -> kn f32. V (col0>=2560): raw f32 -> qkvraw.
__global__ __launch_bounds__(256) void k_gemm_qkv(const f16* __restrict__ A, const f16* __restrict__ Bt,
                                                  float* __restrict__ qkvV, const float* __restrict__ qnw,
                                                  const float* __restrict__ knw, const float* __restrict__ cosb,
                                                  const float* __restrict__ sinb, f16* __restrict__ qr,
                                                  float* __restrict__ kn) {
    __shared__ f16 As[128 * 32];
    __shared__ f16 Bs[128 * 32];
    __shared__ float ssb[256];
    __shared__ f16 xbuf[128 * 128];
    const int K = 2048;
    int tid = threadIdx.x;
    int w = tid >> 6, l = tid & 63, lr = l & 15, lg = l >> 4;
    int wr = w >> 1, wc = w & 1;
    int nwg = gridDim.x * gridDim.y;
    int wid = xcd_remap(blockIdx.y * gridDim.x + blockIdx.x, nwg);
    int row0 = (wid / gridDim.x) * 128, col0 = (wid % gridDim.x) * 128;
    f32x4 zero = {0.f, 0.f, 0.f, 0.f};
    f32x4 acc[4][4];
    #pragma unroll
    for (int m = 0; m < 4; ++m)
        #pragma unroll
        for (int n = 0; n < 4; ++n) acc[m][n] = zero;
    for (int k0 = 0; k0 < K; k0 += 32) {
        #pragma unroll
        for (int p = 0; p < 2; ++p) {
            int id = p * 256 + tid;
            int r = id >> 2, c8 = (id & 3) * 8;
            GLL16(&A[(size_t)(row0 + r) * K + k0 + c8], &As[id * 8]);
            GLL16(&Bt[(size_t)(col0 + r) * K + k0 + c8], &Bs[id * 8]);
        }
        __syncthreads();
        f16x8 a[4], b[4];
        #pragma unroll
        for (int m = 0; m < 4; ++m) a[m] = ld8(&As[(wr*64 + m*16 + lr) * 32 + lg*8]);
        #pragma unroll
        for (int n = 0; n < 4; ++n) b[n] = ld8(&Bs[(wc*64 + n*16 + lr) * 32 + lg*8]);
        #pragma unroll
        for (int m = 0; m < 4; ++m)
            #pragma unroll
            for (int n = 0; n < 4; ++n)
                acc[m][n] = MFMA16(a[m], b[n], acc[m][n]);
        __syncthreads();
    }

    if (col0 >= 2560) {
        // V head: raw f32 store
        #pragma unroll
        for (int m = 0; m < 4; ++m)
            #pragma unroll
            for (int n = 0; n < 4; ++n)
                #pragma unroll
                for (int i = 0; i < 4; ++i)
                    qkvV[(size_t)(row0 + wr*64 + m*16 + lg*4 + i) * 3072 + col0 + wc*64 + n*16 + lr] = acc[m][n][i];
        return;
    }
    // Q or K head: per-row sum of squares (row = 128 cols = this block's width)
    float ss[4][4];
    #pragma unroll
    for (int m = 0; m < 4; ++m)
        #pragma unroll
        for (int i = 0; i < 4; ++i) {
            float s = 0;
            #pragma unroll
            for (int n = 0; n < 4; ++n) s += acc[m][n][i] * acc[m][n][i];
            s += __shfl_xor(s, 1); s += __shfl_xor(s, 2);
            s += __shfl_xor(s, 4); s += __shfl_xor(s, 8);
            ss[m][i] = s;
        }
    if (lr == 0) {
        #pragma unroll
        for (int m = 0; m < 4; ++m)
            #pragma unroll
            for (int i = 0; i < 4; ++i)
                ssb[wc*128 + wr*64 + m*16 + lg*4 + i] = ss[m][i];
    }
    __syncthreads();
    bool isK = (col0 >= 2048);
    #pragma unroll
    for (int m = 0; m < 4; ++m)
        #pragma unroll
        for (int i = 0; i < 4; ++i) {
            int ridx = wr*64 + m*16 + lg*4 + i;
            float rn = rsqrtf((ssb[ridx] + ssb[128 + ridx]) * (1.0f/128.0f) + 1e-6f);
            int r = row0 + ridx;
            #pragma unroll
            for (int n = 0; n < 4; ++n) {
                int dd = wc*64 + n*16 + lr;
                if (isK) {
                    kn[(size_t)r*512 + (col0 - 2048) + dd] = acc[m][n][i] * rn * knw[dd];
                } else {
                    float xn = acc[m][n][i] * rn * qnw[dd];
                    acc[m][n][i] = xn;
                    xbuf[ridx*128 + dd] = (f16)xn;
                }
            }
        }
    if (!isK) {
        __syncthreads();
        const float scl = 0.088388347648318447f * 1.4426950408889634f; // log2(e)/sqrt(128)
        #pragma unroll
        for (int m = 0; m < 4; ++m)
            #pragma unroll
            for (int i = 0; i < 4; ++i) {
                int ridx = wr*64 + m*16 + lg*4 + i;
                int r = row0 + ridx;
                #pragma unroll
                for (int n = 0; n < 4; ++n) {
                    int dd = wc*64 + n*16 + lr;
                    float p = (float)xbuf[ridx*128 + (dd ^ 64)];
                    float rot = (dd < 64) ? -p : p;
                    qr[(size_t)r*2048 + col0 + dd] =
                        (f16)((acc[m][n][i]*cosb[r*128 + dd] + rot*sinb[r*128 + dd]) * scl);
                }
            }
    }
}

// ---------------- plain f16 GEMM (gemm2): C[M][N] = A[M][K] * Bt[N][K]^T, f32 out ----------------
__global__ __launch_bounds__(256) void k_gemm(const f16* __restrict__ A, const f16* __restrict__ Bt,
                                              float* __restrict__ C, int M, int N, int K) {
    __shared__ f16 As[128 * 32];
    __shared__ f16 Bs[128 * 32];
    int tid = threadIdx.x;
    int w = tid >> 6, l = tid & 63, lr = l & 15, lg = l >> 4;
    int wr = w >> 1, wc = w & 1;
    int nwg = gridDim.x * gridDim.y;
    int wid = xcd_remap(blockIdx.y * gridDim.x + blockIdx.x, nwg);
    int row0 = (wid / gridDim.x) * 128, col0 = (wid % gridDim.x) * 128;
    f32x4 zero = {0.f, 0.f, 0.f, 0.f};
    f32x4 acc[4][4];
    #pragma unroll
    for (int m = 0; m < 4; ++m)
        #pragma unroll
        for (int n = 0; n < 4; ++n) acc[m][n] = zero;
    for (int k0 = 0; k0 < K; k0 += 32) {
        #pragma unroll
        for (int p = 0; p < 2; ++p) {
            int id = p * 256 + tid;
            int r = id >> 2, c8 = (id & 3) * 8;
            GLL16(&A[(size_t)(row0 + r) * K + k0 + c8], &As[id * 8]);
            GLL16(&Bt[(size_t)(col0 + r) * K + k0 + c8], &Bs[id * 8]);
        }
        __syncthreads();
        f16x8 a[4], b[4];
        #pragma unroll
        for (int m = 0; m < 4; ++m) a[m] = ld8(&As[(wr*64 + m*16 + lr) * 32 + lg*8]);
        #pragma unroll
        for (int n = 0; n < 4; ++n) b[n] = ld8(&Bs[(wc*64 + n*16 + lr) * 32 + lg*8]);
        #pragma unroll
        for (int m = 0; m < 4; ++m)
            #pragma unroll
            for (int n = 0; n < 4; ++n)
                acc[m][n] = MFMA16(a[m], b[n], acc[m][n]);
        __syncthreads();
    }
    #pragma unroll
    for (int m = 0; m < 4; ++m)
        #pragma unroll
        for (int n = 0; n < 4; ++n)
            #pragma unroll
            for (int i = 0; i < 4; ++i)
                C[(size_t)(row0 + wr*64 + m*16 + lg*4 + i) * N + col0 + wc*64 + n*16 + lr] = acc[m][n][i];
}

// ---------------- merged: sketch stage 1 (blocks 0..1023) + gather (blocks 1024..2047) ----------------
__global__ __launch_bounds__(256) void k_gather_sketch(const int* __restrict__ sel, const float* __restrict__ kn,
                                                       const float* __restrict__ qkv, const float* __restrict__ cosb,
                                                       const float* __restrict__ sinb, const float* __restrict__ iw,
                                                       const float* __restrict__ kronb, f16* __restrict__ Kf,
                                                       f16* __restrict__ VfT, float* __restrict__ T) {
    int bid = blockIdx.x;
    if (bid < 1024) {
        int which = bid >> 9, inner = bid & 511;
        int mb = inner & 31, sa = inner >> 5;
        int c0 = threadIdx.x * 2;
        float a0 = 0, a1 = 0;
        for (int sb = 0; sb < 256; ++sb) {
            int s = sa * 256 + sb;
            float wgt = kronb[mb * 256 + sb] * iw[s];
            const float* src = which ? &qkv[(size_t)s*3072 + 2560] : &kn[(size_t)s*512];
            a0 += wgt * src[c0];
            a1 += wgt * src[c0 + 1];
        }
        float* dst = &T[(size_t)((which*32 + mb)*16 + sa) * 512 + c0];
        dst[0] = a0; dst[1] = a1;
    } else {
        int j = (bid - 1024) * 2 + (threadIdx.x >> 7);
        int t = threadIdx.x & 127;
        int s = sel[j];
        float c = cosb[s*128 + t], sn = sinb[s*128 + t];
        #pragma unroll
        for (int h = 0; h < 4; ++h) {
            float x  = kn[(size_t)s*512 + h*128 + t];
            float pr = kn[(size_t)s*512 + h*128 + (t ^ 64)];
            float rot = (t < 64) ? -pr : pr;
            Kf[(size_t)(h*2688 + j) * 128 + t] = (f16)(x*c + rot*sn);
            float v = qkv[(size_t)s*3072 + 2560 + h*128 + t];
            VfT[(size_t)h*128*2688 + (size_t)t*2688 + j] = (f16)v;
        }
    }
}

// ---------------- sketch stage 2 ----------------
__global__ __launch_bounds__(256) void k_sketch2(const float* __restrict__ T, const float* __restrict__ krona,
                                                 const float* __restrict__ sscale, f16* __restrict__ Kf,
                                                 f16* __restrict__ VfT) {
    int m = blockIdx.x;
    int which = blockIdx.y;
    int ma = m >> 5, mb = m & 31;
    int c0 = threadIdx.x * 2;
    float sc = sscale[0];
    float a0 = 0, a1 = 0;
    #pragma unroll
    for (int sa = 0; sa < 16; ++sa) {
        float ka = krona[ma * 128 + sa];
        const float* t = &T[(size_t)((which*32 + mb)*16 + sa) * 512 + c0];
        a0 += ka * t[0];
        a1 += ka * t[1];
    }
    a0 *= sc; a1 *= sc;
    int key = 2048 + m;
    int h0 = c0 >> 7, d = c0 & 127;
    if (which == 0) {
        Kf[(size_t)(h0*2688 + key)*128 + d]     = (f16)a0;
        Kf[(size_t)(h0*2688 + key)*128 + d + 1] = (f16)a1;
    } else {
        VfT[(size_t)h0*128*2688 + (size_t)d*2688 + key]       = (f16)a0;
        VfT[(size_t)h0*128*2688 + (size_t)(d+1)*2688 + key]   = (f16)a1;
    }
}

// ---------------- flash attention v5 + XCD-swizzled block map ----------------
__global__ __launch_bounds__(256, 2) void k_attn(const f16* __restrict__ qr, const f16* __restrict__ Kf,
                                                 const f16* __restrict__ VfT, f16* __restrict__ out16) {
    __shared__ f16 KT[2][64 * 128];
    __shared__ f16 VT[2][128 * 64];
    __shared__ f16 P[4][32 * 64];
    int nwg = gridDim.x * gridDim.y;
    int wid = xcd_remap(blockIdx.y * gridDim.x + blockIdx.x, nwg);
    int qt = wid % gridDim.x, h = wid / gridDim.x;
    int kvh = h >> 2;
    int tid = threadIdx.x;
    int w = tid >> 6, l = tid & 63, lr = l & 15, lg = l >> 4;
    int q0 = qt * 128 + w * 32;
    const char* Kb = (const char*)(Kf + (size_t)kvh * 2688 * 128);
    const char* Vb = (const char*)(VfT + (size_t)kvh * 128 * 2688);
    char* Pw = (char*)&P[w][0];

    int koff[4], voff[2];
    #pragma unroll
    for (int c = 0; c < 4; ++c) koff[c] = (c*64 + lg*16) ^ ((lr & 7) << 5);
    #pragma unroll
    for (int kw = 0; kw < 2; ++kw) voff[kw] = (kw*64 + lg*16) ^ ((lr & 7) << 4);
    int psw = (lr & 7) << 4;

    int L0 = tid * 16;

    f16x8 aq[2][4];
    #pragma unroll
    for (int hh = 0; hh < 2; ++hh)
        #pragma unroll
        for (int c = 0; c < 4; ++c)
            aq[hh][c] = ld8(&qr[(size_t)(q0 + hh*16 + lr) * 2048 + h*128 + c*32 + lg*8]);

    f32x4 zero = {0.f,0.f,0.f,0.f};
    f32x4 o0[8], o1[8];
    #pragma unroll
    for (int f = 0; f < 8; ++f) { o0[f] = zero; o1[f] = zero; }
    float m0[4], m1[4], ls0[4], ls1[4];
    #pragma unroll
    for (int i = 0; i < 4; ++i) { m0[i] = -1e30f; m1[i] = -1e30f; ls0[i] = 0.f; ls1[i] = 0.f; }

    #define STAGE(buf, kt)  do {                                                          \
        _Pragma("unroll")                                                                  \
        for (int i_ = 0; i_ < 4; ++i_) {                                                   \
            int L = L0 + i_*4096;                                                          \
            int krow = L >> 8, kbc = L & 255;                                              \
            GLL16(Kb + (size_t)((kt) + krow)*256 + (kbc ^ ((krow & 7) << 5)),              \
                  (char*)&KT[buf][0] + L);                                                 \
            int vd = L >> 7, vbc = L & 127;                                                \
            GLL16(Vb + (size_t)vd*5376 + (size_t)(kt)*2 + (vbc ^ ((vd & 7) << 4)),         \
                  (char*)&VT[buf][0] + L);                                                 \
        }                                                                                  \
    } while (0)

    STAGE(0, 0);
    asm volatile("s_waitcnt vmcnt(0)" ::: "memory");
    __syncthreads();

    for (int t = 0; t < 42; ++t) {
        int cur = t & 1;
        if (t < 41) STAGE(cur ^ 1, (t + 1) * 64);
        const char* Kc = (const char*)&KT[cur][0];
        const char* Vc = (const char*)&VT[cur][0];

        f32x4 s0[4], s1[4];
        #pragma unroll
        for (int tt = 0; tt < 4; ++tt) { s0[tt] = zero; s1[tt] = zero; }
        __builtin_amdgcn_s_setprio(1);
        #pragma unroll
        for (int tt = 0; tt < 4; ++tt) {
            #pragma unroll
            for (int c = 0; c < 4; ++c) {
                f16x8 kb = ld8((const f16*)(Kc + (tt*16 + lr)*256 + koff[c]));
                s0[tt] = MFMA16(aq[0][c], kb, s0[tt]);
                s1[tt] = MFMA16(aq[1][c], kb, s1[tt]);
            }
        }
        __builtin_amdgcn_s_setprio(0);

        float tl0[4], tl1[4];
        bool need = false;
        #pragma unroll
        for (int i = 0; i < 4; ++i) {
            tl0[i] = fmaxf(fmaxf(s0[0][i], s0[1][i]), fmaxf(s0[2][i], s0[3][i]));
            tl1[i] = fmaxf(fmaxf(s1[0][i], s1[1][i]), fmaxf(s1[2][i], s1[3][i]));
            need = need || (tl0[i] > m0[i]+8.f) || (tl1[i] > m1[i]+8.f);
        }
        if (__any(need)) {
            f32x4 cf0, cf1;
            #pragma unroll
            for (int i = 0; i < 4; ++i) {
                float a = tl0[i];
                a = fmaxf(a, __shfl_xor(a, 1)); a = fmaxf(a, __shfl_xor(a, 2));
                a = fmaxf(a, __shfl_xor(a, 4)); a = fmaxf(a, __shfl_xor(a, 8));
                float mn0 = fmaxf(m0[i], a);
                cf0[i] = exp2a(m0[i] - mn0); m0[i] = mn0; ls0[i] *= cf0[i];
                float b = tl1[i];
                b = fmaxf(b, __shfl_xor(b, 1)); b = fmaxf(b, __shfl_xor(b, 2));
                b = fmaxf(b, __shfl_xor(b, 4)); b = fmaxf(b, __shfl_xor(b, 8));
                float mn1 = fmaxf(m1[i], b);
                cf1[i] = exp2a(m1[i] - mn1); m1[i] = mn1; ls1[i] *= cf1[i];
            }
            #pragma unroll
            for (int f = 0; f < 8; ++f) { o0[f] *= cf0; o1[f] *= cf1; }
        }
        #pragma unroll
        for (int tt = 0; tt < 4; ++tt)
            #pragma unroll
            for (int i = 0; i < 4; ++i) {
                int r0 = lg*4 + i;
                float p0 = exp2a(s0[tt][i] - m0[i]);
                ls0[i] += p0;
                *(f16*)(Pw + ((r0*128 + (tt*16+lr)*2) ^ ((r0 & 7) << 4))) = (f16)p0;
                int r1 = 16 + r0;
                float p1 = exp2a(s1[tt][i] - m1[i]);
                ls1[i] += p1;
                *(f16*)(Pw + ((r1*128 + (tt*16+lr)*2) ^ ((r1 & 7) << 4))) = (f16)p1;
            }
        asm volatile("s_waitcnt lgkmcnt(0)" ::: "memory");
        __builtin_amdgcn_sched_barrier(0);

        __builtin_amdgcn_s_setprio(1);
        #pragma unroll
        for (int kw = 0; kw < 2; ++kw) {
            f16x8 pa0 = *(const f16x8*)(Pw + ((lr*128 + kw*64 + lg*16) ^ psw));
            f16x8 pa1 = *(const f16x8*)(Pw + (((16+lr)*128 + kw*64 + lg*16) ^ psw));
            #pragma unroll
            for (int f = 0; f < 8; ++f) {
                f16x8 vb = ld8((const f16*)(Vc + (f*16 + lr)*128 + voff[kw]));
                o0[f] = MFMA16(pa0, vb, o0[f]);
                o1[f] = MFMA16(pa1, vb, o1[f]);
            }
        }
        __builtin_amdgcn_s_setprio(0);
        asm volatile("s_waitcnt vmcnt(0)" ::: "memory");
        __syncthreads();
    }

    #pragma unroll
    for (int i = 0; i < 4; ++i) {
        float a = ls0[i];
        a += __shfl_xor(a, 1); a += __shfl_xor(a, 2); a += __shfl_xor(a, 4); a += __shfl_xor(a, 8);
        float inv0 = 1.0f / a;
        float b = ls1[i];
        b += __shfl_xor(b, 1); b += __shfl_xor(b, 2); b += __shfl_xor(b, 4); b += __shfl_xor(b, 8);
        float inv1 = 1.0f / b;
        #pragma unroll
        for (int f = 0; f < 8; ++f) {
            out16[(size_t)(q0 + lg*4 + i) * 2048 + h*128 + f*16 + lr]      = (f16)(o0[f][i] * inv0);
            out16[(size_t)(q0 + 16 + lg*4 + i) * 2048 + h*128 + f*16 + lr] = (f16)(o1[f][i] * inv1);
        }
    }
    #undef STAGE
}

extern "C" void kernel_launch(void* const* d_in, const int* in_sizes, int n_in,
                              void* d_out, int out_size, void* d_ws, size_t ws_size,
                              hipStream_t stream) {
    const float* h     = (const float*)d_in[0];
    const float* wq    = (const float*)d_in[1];
    const float* wk    = (const float*)d_in[2];
    const float* wv    = (const float*)d_in[3];
    const float* wo    = (const float*)d_in[4];
    const float* qnw   = (const float*)d_in[5];
    const float* knw   = (const float*)d_in[6];
    const float* sw1   = (const float*)d_in[7];
    const float* sb1   = (const float*)d_in[8];
    const float* sw2   = (const float*)d_in[9];
    const float* sb2   = (const float*)d_in[10];
    const float* sscal = (const float*)d_in[11];
    const float* ka    = (const float*)d_in[12];
    const float* kb    = (const float*)d_in[13];
    const float* cosb  = (const float*)d_in[14];
    const float* sinb  = (const float*)d_in[15];
    float* outp = (float*)d_out;

    char* ws = (char*)d_ws;
    size_t off = 0;
    f16*    h16    = (f16*)(ws + off);   off += (size_t)4096*2048*2;
    f16*    wqkvt  = (f16*)(ws + off);   off += (size_t)3072*2048*2;
    f16*    wot    = (f16*)(ws + off);   off += (size_t)2048*2048*2;
    float*  qkvraw = (float*)(ws + off); off += (size_t)4096*3072*4;
    f16*    qr     = (f16*)(ws + off);   off += (size_t)4096*2048*2;
    float*  kn     = (float*)(ws + off); off += (size_t)4096*512*4;
    f16*    attn16 = (f16*)(ws + off);   off += (size_t)4096*2048*2;
    float*  T      = (float*)(ws + off); off += (size_t)2*32*16*512*4;
    f16*    Kf     = (f16*)(ws + off);   off += (size_t)4*2688*128*2;
    f16*    VfT    = (f16*)(ws + off);   off += (size_t)4*128*2688*2;
    double* logitsD= (double*)(ws + off);off += (size_t)4096*8;
    float*  iw     = (float*)(ws + off); off += (size_t)4096*4;
    int*    sel    = (int*)(ws + off);   off += (size_t)2048*4;
    double* part   = (double*)qkvraw;   // aliases qkvraw; consumed by mlp2 before gemm writes V cols

    k_mlp1t<<<10752, 256, 0, stream>>>(h, sw1, wq, wk, wv, wo, part, h16, wqkvt, wot);
    k_mlp2<<<1024, 256, 0, stream>>>(part, sb1, sw2, sb2, logitsD, iw);
    k_topk<<<1, 1024, 0, stream>>>(logitsD, sel);
    k_gemm_qkv<<<dim3(24,32), 256, 0, stream>>>(h16, wqkvt, qkvraw, qnw, knw, cosb, sinb, qr, kn);
    k_gather_sketch<<<2048, 256, 0, stream>>>(sel, kn, qkvraw, cosb, sinb, iw, kb, Kf, VfT, T);
    k_sketch2<<<dim3(640,2), 256, 0, stream>>>(T, ka, sscal, Kf, VfT);
    k_attn<<<dim3(32,16), 256, 0, stream>>>(qr, Kf, VfT, attn16);
    k_gemm<<<dim3(16,32), 256, 0, stream>>>(attn16, wot, outp, 4096, 2048, 2048);
}

// Round 15
// 395.394 us; speedup vs baseline: 1.1451x; 1.1451x over previous
//
#include <hip/hip_runtime.h>
#include <math.h>

typedef _Float16 f16;
typedef f16 f16x8 __attribute__((ext_vector_type(8)));
typedef float f32x4 __attribute__((ext_vector_type(4)));

#define MFMA16(a,b,c) __builtin_amdgcn_mfma_f32_16x16x32_f16(a,b,c,0,0,0)

static __device__ __forceinline__ f16x8 ld8(const f16* p) { return *(const f16x8*)p; }

static __device__ __forceinline__ float exp2a(float x) {
    float r; asm("v_exp_f32 %0, %1" : "=v"(r) : "v"(x)); return r;
}

// bijective XCD-chunking remap (m204)
static __device__ __forceinline__ int xcd_remap(int flat, int nwg) {
    int q = nwg >> 3, r = nwg & 7;
    int xcd = flat & 7, pos = flat >> 3;
    return (xcd < r ? xcd * (q + 1) : r * (q + 1) + (xcd - r) * q) + pos;
}

#if __has_builtin(__builtin_amdgcn_global_load_lds)
#define GLL16(g, lptr) __builtin_amdgcn_global_load_lds((const __attribute__((address_space(1))) void*)(g), (__attribute__((address_space(3))) void*)(lptr), 16, 0, 0)
#else
#define GLL16(g, lptr) do { *(int4*)(lptr) = *(const int4*)(g); } while (0)
#endif

// ---------------- gating MLP stage 1: f64 partial GEMM (M=4096,N=64,K-split=4) ----------------
__global__ __launch_bounds__(256) void k_mlp1(const float* __restrict__ h, const float* __restrict__ w1,
                                              double* __restrict__ part, f16* __restrict__ h16) {
    __shared__ float hs[64 * 68];
    __shared__ float ws[64 * 64];
    int rb = blockIdx.x, ks = blockIdx.y;
    int tid = threadIdx.x;
    int jq = tid & 15, rt = tid >> 4;
    double acc[4][4];
    #pragma unroll
    for (int r = 0; r < 4; ++r)
        #pragma unroll
        for (int q = 0; q < 4; ++q) acc[r][q] = 0.0;

    float4 hreg[4], wreg[4];
    int hrow[4], hcq[4], wc[4], wq[4];
    #pragma unroll
    for (int i = 0; i < 4; ++i) {
        int fl = i * 256 + tid;
        hrow[i] = fl >> 4; hcq[i] = fl & 15;
        wc[i] = fl >> 4;   wq[i] = fl & 15;
    }
    #define LOADCH(c8) do {                                                                  \
        _Pragma("unroll")                                                                     \
        for (int i = 0; i < 4; ++i) {                                                         \
            hreg[i] = *(const float4*)&h[(size_t)(rb*64 + hrow[i])*2048 + ks*512 + (c8)*64 + hcq[i]*4]; \
            wreg[i] = *(const float4*)&w1[(size_t)(ks*512 + (c8)*64 + wc[i])*64 + wq[i]*4];   \
        }                                                                                     \
    } while (0)

    LOADCH(0);
    for (int c8 = 0; c8 < 8; ++c8) {
        __syncthreads();
        #pragma unroll
        for (int i = 0; i < 4; ++i) {
            *(float4*)&hs[hrow[i]*68 + hcq[i]*4] = hreg[i];
            *(float4*)&ws[wc[i]*64 + wq[i]*4] = wreg[i];
            const float* hp = (const float*)&hreg[i];
            f16 h4[4];
            #pragma unroll
            for (int z = 0; z < 4; ++z) h4[z] = (f16)hp[z];
            *(float*)&h16[(size_t)(rb*64 + hrow[i])*2048 + ks*512 + c8*64 + hcq[i]*4] = *(float*)h4;
            *(float*)(&h16[(size_t)(rb*64 + hrow[i])*2048 + ks*512 + c8*64 + hcq[i]*4 + 2]) = *(((float*)h4)+1);
        }
        __syncthreads();
        if (c8 < 7) LOADCH(c8 + 1);
        #pragma unroll 4
        for (int cg = 0; cg < 64; cg += 4) {
            float4 ha[4], wa[4];
            #pragma unroll
            for (int r = 0; r < 4; ++r) ha[r] = *(const float4*)&hs[(rt + 16*r)*68 + cg];
            #pragma unroll
            for (int cc = 0; cc < 4; ++cc) wa[cc] = *(const float4*)&ws[(cg + cc)*64 + jq*4];
            #pragma unroll
            for (int cc = 0; cc < 4; ++cc) {
                const float* wap = (const float*)&wa[cc];
                double wd0 = (double)wap[0], wd1 = (double)wap[1], wd2 = (double)wap[2], wd3 = (double)wap[3];
                #pragma unroll
                for (int r = 0; r < 4; ++r) {
                    double hv = (double)((const float*)&ha[r])[cc];
                    acc[r][0] = fma(hv, wd0, acc[r][0]);
                    acc[r][1] = fma(hv, wd1, acc[r][1]);
                    acc[r][2] = fma(hv, wd2, acc[r][2]);
                    acc[r][3] = fma(hv, wd3, acc[r][3]);
                }
            }
        }
    }
    #pragma unroll
    for (int r = 0; r < 4; ++r)
        #pragma unroll
        for (int q = 0; q < 4; ++q)
            part[((size_t)ks*4096 + rb*64 + rt + 16*r)*64 + jq*4 + q] = acc[r][q];
    #undef LOADCH
}

// ---------------- gating MLP stage 2 ----------------
__global__ __launch_bounds__(256) void k_mlp2(const double* __restrict__ part, const float* __restrict__ b1,
                                              const float* __restrict__ w2, const float* __restrict__ b2,
                                              double* __restrict__ logitsD, float* __restrict__ iw) {
    int tid = threadIdx.x;
    int j = tid & 63, rq = tid >> 6;
    int row = blockIdx.x * 4 + rq;
    double s = part[(size_t)row*64 + j] + part[((size_t)4096 + row)*64 + j]
             + part[((size_t)8192 + row)*64 + j] + part[((size_t)12288 + row)*64 + j];
    double t = tanh(s + (double)b1[j]);
    double v = t * (double)w2[j];
    #pragma unroll
    for (int o = 32; o > 0; o >>= 1) v += __shfl_down(v, o);
    if (j == 0) {
        double lg = v + (double)b2[0] - 1.8562979903656263; // log(4096/640)
        logitsD[row] = lg;
        iw[row] = (float)(1.0 / (1.0 + exp(-lg)));
    }
}

// ---------------- all weight transposes in one launch ----------------
__global__ __launch_bounds__(256) void k_transpose_all(const float* __restrict__ wq, const float* __restrict__ wk,
                                                       const float* __restrict__ wv, const float* __restrict__ wo,
                                                       f16* __restrict__ wqkvt, f16* __restrict__ wot) {
    __shared__ float tile[32][33];
    int bx = blockIdx.x;
    const float* in; int inCols, colBase, rowOff; f16* out;
    if (bx < 64)      { in = wq; inCols = 2048; colBase = bx * 32;        rowOff = colBase;        out = wqkvt; }
    else if (bx < 80) { in = wk; inCols = 512;  colBase = (bx - 64) * 32; rowOff = 2048 + colBase; out = wqkvt; }
    else if (bx < 96) { in = wv; inCols = 512;  colBase = (bx - 80) * 32; rowOff = 2560 + colBase; out = wqkvt; }
    else              { in = wo; inCols = 2048; colBase = (bx - 96) * 32; rowOff = colBase;        out = wot; }
    int tx = threadIdx.x, ty = threadIdx.y;
    int x = colBase + tx;
    int y0 = blockIdx.y * 32;
    #pragma unroll
    for (int i = 0; i < 4; ++i)
        tile[ty + i*8][tx] = in[(size_t)(y0 + ty + i*8) * inCols + x];
    __syncthreads();
    #pragma unroll
    for (int i = 0; i < 4; ++i)
        out[(size_t)(rowOff + ty + i*8) * 2048 + y0 + tx] = (f16)tile[tx][ty + i*8];
}

// ---------------- top-2048 of 4096 via MSB radix select (order-free set) ----------------
__global__ __launch_bounds__(1024) void k_topk(const double* __restrict__ logitsD, int* __restrict__ sel) {
    __shared__ unsigned long long keys[4096];
    __shared__ unsigned int hist[2048];
    __shared__ unsigned int bcast[2];
    __shared__ unsigned int cA, cB;
    int tid = threadIdx.x;
    for (int i = tid; i < 4096; i += 1024) {
        unsigned long long u = (unsigned long long)__double_as_longlong(logitsD[i]);
        keys[i] = (u >> 63) ? ~u : (u | 0x8000000000000000ull);
    }
    if (tid == 0) { cA = 0; cB = 0; }
    unsigned long long Tpart = 0;
    unsigned int need = 2048;
    #pragma unroll 1
    for (int lvl = 0; lvl < 6; ++lvl) {
        int shift = (lvl < 5) ? (53 - 11*lvl) : 0;
        int width = (lvl < 5) ? 11 : 9;
        unsigned int nb = 1u << width;
        int hiShift = shift + width;
        for (int i = tid; i < (int)nb; i += 1024) hist[i] = 0;
        __syncthreads();
        for (int i = tid; i < 4096; i += 1024) {
            unsigned long long k = keys[i];
            bool cand = (lvl == 0) || ((k >> hiShift) == (Tpart >> hiShift));
            if (cand) atomicAdd(&hist[(unsigned int)(k >> shift) & (nb - 1u)], 1u);
        }
        __syncthreads();
        if (tid < 64) {
            int chunk = (int)nb >> 6;
            int base = (int)nb - (tid + 1) * chunk;
            unsigned int sum = 0;
            for (int jj = 0; jj < chunk; ++jj) sum += hist[base + jj];
            unsigned int pre = sum;
            #pragma unroll
            for (int o = 1; o < 64; o <<= 1) {
                unsigned int t = __shfl_up(pre, o);
                if (tid >= o) pre += t;
            }
            unsigned int preEx = pre - sum;
            if (preEx < need && need <= pre) {
                unsigned int cum = preEx;
                for (int jj = chunk - 1; jj >= 0; --jj) {
                    unsigned int c = hist[base + jj];
                    if (cum + c >= need) { bcast[0] = (unsigned int)(base + jj); bcast[1] = need - cum; break; }
                    cum += c;
                }
            }
        }
        __syncthreads();
        Tpart |= ((unsigned long long)bcast[0]) << shift;
        need = bcast[1];
        __syncthreads();
    }
    unsigned int G = 2048 - need;
    for (int i = tid; i < 4096; i += 1024) {
        unsigned long long k = keys[i];
        if (k > Tpart) { unsigned int p = atomicAdd(&cA, 1u); sel[p] = i; }
        else if (k == Tpart) { unsigned int q = atomicAdd(&cB, 1u); if (q < need) sel[G + q] = i; }
    }
}

// ---------------- f16 GEMM: C[M][N] = A[M][K] * Bt[N][K]^T, f32 out; XCD-swizzled block map ----------------
__global__ __launch_bounds__(256) void k_gemm(const f16* __restrict__ A, const f16* __restrict__ Bt,
                                              float* __restrict__ C, int M, int N, int K) {
    __shared__ f16 As[128 * 32];
    __shared__ f16 Bs[128 * 32];
    int tid = threadIdx.x;
    int w = tid >> 6, l = tid & 63, lr = l & 15, lg = l >> 4;
    int wr = w >> 1, wc = w & 1;
    int nwg = gridDim.x * gridDim.y;
    int wid = xcd_remap(blockIdx.y * gridDim.x + blockIdx.x, nwg);
    int row0 = (wid / gridDim.x) * 128, col0 = (wid % gridDim.x) * 128;
    f32x4 zero = {0.f, 0.f, 0.f, 0.f};
    f32x4 acc[4][4];
    #pragma unroll
    for (int m = 0; m < 4; ++m)
        #pragma unroll
        for (int n = 0; n < 4; ++n) acc[m][n] = zero;
    for (int k0 = 0; k0 < K; k0 += 32) {
        #pragma unroll
        for (int p = 0; p < 2; ++p) {
            int id = p * 256 + tid;
            int r = id >> 2, c8 = (id & 3) * 8;
            GLL16(&A[(size_t)(row0 + r) * K + k0 + c8], &As[id * 8]);
            GLL16(&Bt[(size_t)(col0 + r) * K + k0 + c8], &Bs[id * 8]);
        }
        __syncthreads();
        f16x8 a[4], b[4];
        #pragma unroll
        for (int m = 0; m < 4; ++m) a[m] = ld8(&As[(wr*64 + m*16 + lr) * 32 + lg*8]);
        #pragma unroll
        for (int n = 0; n < 4; ++n) b[n] = ld8(&Bs[(wc*64 + n*16 + lr) * 32 + lg*8]);
        #pragma unroll
        for (int m = 0; m < 4; ++m)
            #pragma unroll
            for (int n = 0; n < 4; ++n)
                acc[m][n] = MFMA16(a[m], b[n], acc[m][n]);
        __syncthreads();
    }
    #pragma unroll
    for (int m = 0; m < 4; ++m)
        #pragma unroll
        for (int n = 0; n < 4; ++n)
            #pragma unroll
            for (int i = 0; i < 4; ++i)
                C[(size_t)(row0 + wr*64 + m*16 + lg*4 + i) * N + col0 + wc*64 + n*16 + lr] = acc[m][n][i];
}

// ---------------- fused q-norm+RoPE (waves 0-3) and k-norm (wave 4) ----------------
__global__ __launch_bounds__(320) void k_norm(const float* __restrict__ qkv, const float* __restrict__ qnw,
                                              const float* __restrict__ knw, const float* __restrict__ cosb,
                                              const float* __restrict__ sinb, f16* __restrict__ qr,
                                              float* __restrict__ kn) {
    int s = blockIdx.x;
    int tid = threadIdx.x;
    if (tid < 256) {
        int h = tid >> 4, ln = tid & 15, d0 = ln * 8;
        const float* src = &qkv[(size_t)s * 3072 + h * 128 + d0];
        float4 a = *(const float4*)src, b = *(const float4*)(src + 4);
        float x[8] = {a.x,a.y,a.z,a.w,b.x,b.y,b.z,b.w};
        float ss = 0;
        #pragma unroll
        for (int j = 0; j < 8; ++j) ss += x[j]*x[j];
        ss += __shfl_xor(ss,1); ss += __shfl_xor(ss,2); ss += __shfl_xor(ss,4); ss += __shfl_xor(ss,8);
        float rn = rsqrtf(ss * (1.0f/128.0f) + 1e-6f);
        float xn[8];
        #pragma unroll
        for (int j = 0; j < 8; ++j) xn[j] = x[j] * rn * qnw[d0 + j];
        const float scl = 0.088388347648318447f * 1.4426950408889634f; // log2(e)/sqrt(128)
        f16x8 o;
        #pragma unroll
        for (int j = 0; j < 8; ++j) {
            float pr = __shfl_xor(xn[j], 8);
            float rot = (ln < 8) ? -pr : pr;
            int d = d0 + j;
            o[j] = (f16)((xn[j]*cosb[s*128 + d] + rot*sinb[s*128 + d]) * scl);
        }
        *(f16x8*)&qr[(size_t)s * 2048 + h * 128 + d0] = o;
    } else {
        int t2 = tid - 256;
        int h = t2 >> 4, ln = t2 & 15, d0 = ln * 8;
        const float* src = &qkv[(size_t)s * 3072 + 2048 + h * 128 + d0];
        float4 a = *(const float4*)src, b = *(const float4*)(src + 4);
        float x[8] = {a.x,a.y,a.z,a.w,b.x,b.y,b.z,b.w};
        float ss = 0;
        #pragma unroll
        for (int j = 0; j < 8; ++j) ss += x[j]*x[j];
        ss += __shfl_xor(ss,1); ss += __shfl_xor(ss,2); ss += __shfl_xor(ss,4); ss += __shfl_xor(ss,8);
        float rn = rsqrtf(ss * (1.0f/128.0f) + 1e-6f);
        float o[8];
        #pragma unroll
        for (int j = 0; j < 8; ++j) o[j] = x[j] * rn * knw[d0 + j];
        float* dst = &kn[(size_t)s*512 + h*128 + d0];
        *(float4*)dst = make_float4(o[0],o[1],o[2],o[3]);
        *(float4*)(dst+4) = make_float4(o[4],o[5],o[6],o[7]);
    }
}

// ---------------- merged: sketch stage 1 (blocks 0..1023) + gather (blocks 1024..2047) ----------------
__global__ __launch_bounds__(256) void k_gather_sketch(const int* __restrict__ sel, const float* __restrict__ kn,
                                                       const float* __restrict__ qkv, const float* __restrict__ cosb,
                                                       const float* __restrict__ sinb, const float* __restrict__ iw,
                                                       const float* __restrict__ kronb, f16* __restrict__ Kf,
                                                       f16* __restrict__ VfT, float* __restrict__ T) {
    int bid = blockIdx.x;
    if (bid < 1024) {
        int which = bid >> 9, inner = bid & 511;
        int mb = inner & 31, sa = inner >> 5;
        int c0 = threadIdx.x * 2;
        float a0 = 0, a1 = 0;
        for (int sb = 0; sb < 256; ++sb) {
            int s = sa * 256 + sb;
            float wgt = kronb[mb * 256 + sb] * iw[s];
            const float* src = which ? &qkv[(size_t)s*3072 + 2560] : &kn[(size_t)s*512];
            a0 += wgt * src[c0];
            a1 += wgt * src[c0 + 1];
        }
        float* dst = &T[(size_t)((which*32 + mb)*16 + sa) * 512 + c0];
        dst[0] = a0; dst[1] = a1;
    } else {
        int j = (bid - 1024) * 2 + (threadIdx.x >> 7);
        int t = threadIdx.x & 127;
        int s = sel[j];
        float c = cosb[s*128 + t], sn = sinb[s*128 + t];
        #pragma unroll
        for (int h = 0; h < 4; ++h) {
            float x  = kn[(size_t)s*512 + h*128 + t];
            float pr = kn[(size_t)s*512 + h*128 + (t ^ 64)];
            float rot = (t < 64) ? -pr : pr;
            Kf[(size_t)(h*2688 + j) * 128 + t] = (f16)(x*c + rot*sn);
            float v = qkv[(size_t)s*3072 + 2560 + h*128 + t];
            VfT[(size_t)h*128*2688 + (size_t)t*2688 + j] = (f16)v;
        }
    }
}

// ---------------- sketch stage 2 ----------------
__global__ __launch_bounds__(256) void k_sketch2(const float* __restrict__ T, const float* __restrict__ krona,
                                                 const float* __restrict__ sscale, f16* __restrict__ Kf,
                                                 f16* __restrict__ VfT) {
    int m = blockIdx.x;
    int which = blockIdx.y;
    int ma = m >> 5, mb = m & 31;
    int c0 = threadIdx.x * 2;
    float sc = sscale[0];
    float a0 = 0, a1 = 0;
    #pragma unroll
    for (int sa = 0; sa < 16; ++sa) {
        float ka = krona[ma * 128 + sa];
        const float* t = &T[(size_t)((which*32 + mb)*16 + sa) * 512 + c0];
        a0 += ka * t[0];
        a1 += ka * t[1];
    }
    a0 *= sc; a1 *= sc;
    int key = 2048 + m;
    int h0 = c0 >> 7, d = c0 & 127;
    if (which == 0) {
        Kf[(size_t)(h0*2688 + key)*128 + d]     = (f16)a0;
        Kf[(size_t)(h0*2688 + key)*128 + d + 1] = (f16)a1;
    } else {
        VfT[(size_t)h0*128*2688 + (size_t)d*2688 + key]       = (f16)a0;
        VfT[(size_t)h0*128*2688 + (size_t)(d+1)*2688 + key]   = (f16)a1;
    }
}

// ---------------- flash attention v5 + XCD-swizzled block map ----------------
__global__ __launch_bounds__(256, 2) void k_attn(const f16* __restrict__ qr, const f16* __restrict__ Kf,
                                                 const f16* __restrict__ VfT, f16* __restrict__ out16) {
    __shared__ f16 KT[2][64 * 128];
    __shared__ f16 VT[2][128 * 64];
    __shared__ f16 P[4][32 * 64];
    int nwg = gridDim.x * gridDim.y;
    int wid = xcd_remap(blockIdx.y * gridDim.x + blockIdx.x, nwg);
    int qt = wid % gridDim.x, h = wid / gridDim.x;
    int kvh = h >> 2;
    int tid = threadIdx.x;
    int w = tid >> 6, l = tid & 63, lr = l & 15, lg = l >> 4;
    int q0 = qt * 128 + w * 32;
    const char* Kb = (const char*)(Kf + (size_t)kvh * 2688 * 128);
    const char* Vb = (const char*)(VfT + (size_t)kvh * 128 * 2688);
    char* Pw = (char*)&P[w][0];

    int koff[4], voff[2];
    #pragma unroll
    for (int c = 0; c < 4; ++c) koff[c] = (c*64 + lg*16) ^ ((lr & 7) << 5);
    #pragma unroll
    for (int kw = 0; kw < 2; ++kw) voff[kw] = (kw*64 + lg*16) ^ ((lr & 7) << 4);
    int psw = (lr & 7) << 4;

    int L0 = tid * 16;

    f16x8 aq[2][4];
    #pragma unroll
    for (int hh = 0; hh < 2; ++hh)
        #pragma unroll
        for (int c = 0; c < 4; ++c)
            aq[hh][c] = ld8(&qr[(size_t)(q0 + hh*16 + lr) * 2048 + h*128 + c*32 + lg*8]);

    f32x4 zero = {0.f,0.f,0.f,0.f};
    f32x4 o0[8], o1[8];
    #pragma unroll
    for (int f = 0; f < 8; ++f) { o0[f] = zero; o1[f] = zero; }
    float m0[4], m1[4], ls0[4], ls1[4];
    #pragma unroll
    for (int i = 0; i < 4; ++i) { m0[i] = -1e30f; m1[i] = -1e30f; ls0[i] = 0.f; ls1[i] = 0.f; }

    #define STAGE(buf, kt)  do {                                                          \
        _Pragma("unroll")                                                                  \
        for (int i_ = 0; i_ < 4; ++i_) {                                                   \
            int L = L0 + i_*4096;                                                          \
            int krow = L >> 8, kbc = L & 255;                                              \
            GLL16(Kb + (size_t)((kt) + krow)*256 + (kbc ^ ((krow & 7) << 5)),              \
                  (char*)&KT[buf][0] + L);                                                 \
            int vd = L >> 7, vbc = L & 127;                                                \
            GLL16(Vb + (size_t)vd*5376 + (size_t)(kt)*2 + (vbc ^ ((vd & 7) << 4)),         \
                  (char*)&VT[buf][0] + L);                                                 \
        }                                                                                  \
    } while (0)

    STAGE(0, 0);
    asm volatile("s_waitcnt vmcnt(0)" ::: "memory");
    __syncthreads();

    for (int t = 0; t < 42; ++t) {
        int cur = t & 1;
        if (t < 41) STAGE(cur ^ 1, (t + 1) * 64);
        const char* Kc = (const char*)&KT[cur][0];
        const char* Vc = (const char*)&VT[cur][0];

        f32x4 s0[4], s1[4];
        #pragma unroll
        for (int tt = 0; tt < 4; ++tt) { s0[tt] = zero; s1[tt] = zero; }
        __builtin_amdgcn_s_setprio(1);
        #pragma unroll
        for (int tt = 0; tt < 4; ++tt) {
            #pragma unroll
            for (int c = 0; c < 4; ++c) {
                f16x8 kb = ld8((const f16*)(Kc + (tt*16 + lr)*256 + koff[c]));
                s0[tt] = MFMA16(aq[0][c], kb, s0[tt]);
                s1[tt] = MFMA16(aq[1][c], kb, s1[tt]);
            }
        }
        __builtin_amdgcn_s_setprio(0);

        float tl0[4], tl1[4];
        bool need = false;
        #pragma unroll
        for (int i = 0; i < 4; ++i) {
            tl0[i] = fmaxf(fmaxf(s0[0][i], s0[1][i]), fmaxf(s0[2][i], s0[3][i]));
            tl1[i] = fmaxf(fmaxf(s1[0][i], s1[1][i]), fmaxf(s1[2][i], s1[3][i]));
            need = need || (tl0[i] > m0[i]+8.f) || (tl1[i] > m1[i]+8.f);
        }
        if (__any(need)) {
            f32x4 cf0, cf1;
            #pragma unroll
            for (int i = 0; i < 4; ++i) {
                float a = tl0[i];
                a = fmaxf(a, __shfl_xor(a, 1)); a = fmaxf(a, __shfl_xor(a, 2));
                a = fmaxf(a, __shfl_xor(a, 4)); a = fmaxf(a, __shfl_xor(a, 8));
                float mn0 = fmaxf(m0[i], a);
                cf0[i] = exp2a(m0[i] - mn0); m0[i] = mn0; ls0[i] *= cf0[i];
                float b = tl1[i];
                b = fmaxf(b, __shfl_xor(b, 1)); b = fmaxf(b, __shfl_xor(b, 2));
                b = fmaxf(b, __shfl_xor(b, 4)); b = fmaxf(b, __shfl_xor(b, 8));
                float mn1 = fmaxf(m1[i], b);
                cf1[i] = exp2a(m1[i] - mn1); m1[i] = mn1; ls1[i] *= cf1[i];
            }
            #pragma unroll
            for (int f = 0; f < 8; ++f) { o0[f] *= cf0; o1[f] *= cf1; }
        }
        #pragma unroll
        for (int tt = 0; tt < 4; ++tt)
            #pragma unroll
            for (int i = 0; i < 4; ++i) {
                int r0 = lg*4 + i;
                float p0 = exp2a(s0[tt][i] - m0[i]);
                ls0[i] += p0;
                *(f16*)(Pw + ((r0*128 + (tt*16+lr)*2) ^ ((r0 & 7) << 4))) = (f16)p0;
                int r1 = 16 + r0;
                float p1 = exp2a(s1[tt][i] - m1[i]);
                ls1[i] += p1;
                *(f16*)(Pw + ((r1*128 + (tt*16+lr)*2) ^ ((r1 & 7) << 4))) = (f16)p1;
            }
        asm volatile("s_waitcnt lgkmcnt(0)" ::: "memory");
        __builtin_amdgcn_sched_barrier(0);

        __builtin_amdgcn_s_setprio(1);
        #pragma unroll
        for (int kw = 0; kw < 2; ++kw) {
            f16x8 pa0 = *(const f16x8*)(Pw + ((lr*128 + kw*64 + lg*16) ^ psw));
            f16x8 pa1 = *(const f16x8*)(Pw + (((16+lr)*128 + kw*64 + lg*16) ^ psw));
            #pragma unroll
            for (int f = 0; f < 8; ++f) {
                f16x8 vb = ld8((const f16*)(Vc + (f*16 + lr)*128 + voff[kw]));
                o0[f] = MFMA16(pa0, vb, o0[f]);
                o1[f] = MFMA16(pa1, vb, o1[f]);
            }
        }
        __builtin_amdgcn_s_setprio(0);
        asm volatile("s_waitcnt vmcnt(0)" ::: "memory");
        __syncthreads();
    }

    #pragma unroll
    for (int i = 0; i < 4; ++i) {
        float a = ls0[i];
        a += __shfl_xor(a, 1); a += __shfl_xor(a, 2); a += __shfl_xor(a, 4); a += __shfl_xor(a, 8);
        float inv0 = 1.0f / a;
        float b = ls1[i];
        b += __shfl_xor(b, 1); b += __shfl_xor(b, 2); b += __shfl_xor(b, 4); b += __shfl_xor(b, 8);
        float inv1 = 1.0f / b;
        #pragma unroll
        for (int f = 0; f < 8; ++f) {
            out16[(size_t)(q0 + lg*4 + i) * 2048 + h*128 + f*16 + lr]      = (f16)(o0[f][i] * inv0);
            out16[(size_t)(q0 + 16 + lg*4 + i) * 2048 + h*128 + f*16 + lr] = (f16)(o1[f][i] * inv1);
        }
    }
    #undef STAGE
}

extern "C" void kernel_launch(void* const* d_in, const int* in_sizes, int n_in,
                              void* d_out, int out_size, void* d_ws, size_t ws_size,
                              hipStream_t stream) {
    const float* h     = (const float*)d_in[0];
    const float* wq    = (const float*)d_in[1];
    const float* wk    = (const float*)d_in[2];
    const float* wv    = (const float*)d_in[3];
    const float* wo    = (const float*)d_in[4];
    const float* qnw   = (const float*)d_in[5];
    const float* knw   = (const float*)d_in[6];
    const float* sw1   = (const float*)d_in[7];
    const float* sb1   = (const float*)d_in[8];
    const float* sw2   = (const float*)d_in[9];
    const float* sb2   = (const float*)d_in[10];
    const float* sscal = (const float*)d_in[11];
    const float* ka    = (const float*)d_in[12];
    const float* kb    = (const float*)d_in[13];
    const float* cosb  = (const float*)d_in[14];
    const float* sinb  = (const float*)d_in[15];
    float* outp = (float*)d_out;

    char* ws = (char*)d_ws;
    size_t off = 0;
    f16*    h16    = (f16*)(ws + off);   off += (size_t)4096*2048*2;
    f16*    wqkvt  = (f16*)(ws + off);   off += (size_t)3072*2048*2;
    f16*    wot    = (f16*)(ws + off);   off += (size_t)2048*2048*2;
    float*  qkvraw = (float*)(ws + off); off += (size_t)4096*3072*4;
    f16*    qr     = (f16*)(ws + off);   off += (size_t)4096*2048*2;
    float*  kn     = (float*)(ws + off); off += (size_t)4096*512*4;
    f16*    attn16 = (f16*)(ws + off);   off += (size_t)4096*2048*2;
    float*  T      = (float*)(ws + off); off += (size_t)2*32*16*512*4;
    f16*    Kf     = (f16*)(ws + off);   off += (size_t)4*2688*128*2;
    f16*    VfT    = (f16*)(ws + off);   off += (size_t)4*128*2688*2;
    double* logitsD= (double*)(ws + off);off += (size_t)4096*8;
    float*  iw     = (float*)(ws + off); off += (size_t)4096*4;
    int*    sel    = (int*)(ws + off);   off += (size_t)2048*4;
    double* part   = (double*)qkvraw;   // aliases qkvraw (overwritten later by k_gemm)

    k_mlp1<<<dim3(64,4), 256, 0, stream>>>(h, sw1, part, h16);
    k_mlp2<<<1024, 256, 0, stream>>>(part, sb1, sw2, sb2, logitsD, iw);
    k_transpose_all<<<dim3(160,64), dim3(32,8), 0, stream>>>(wq, wk, wv, wo, wqkvt, wot);
    k_topk<<<1, 1024, 0, stream>>>(logitsD, sel);
    k_gemm<<<dim3(24,32), 256, 0, stream>>>(h16, wqkvt, qkvraw, 4096, 3072, 2048);
    k_norm<<<4096, 320, 0, stream>>>(qkvraw, qnw, knw, cosb, sinb, qr, kn);
    k_gather_sketch<<<2048, 256, 0, stream>>>(sel, kn, qkvraw, cosb, sinb, iw, kb, Kf, VfT, T);
    k_sketch2<<<dim3(640,2), 256, 0, stream>>>(T, ka, sscal, Kf, VfT);
    k_attn<<<dim3(32,16), 256, 0, stream>>>(qr, Kf, VfT, attn16);
    k_gemm<<<dim3(16,32), 256, 0, stream>>>(attn16, wot, outp, 4096, 2048, 2048);
}